// Round 2
// baseline (199.216 us; speedup 1.0000x reference)
//
#include <hip/hip_runtime.h>

#define T_TOKENS 2048
#define N_EXPERTS 8
#define ROWS (T_TOKENS * 2)      // T * TOPK
#define I_DIM 2048
#define H_DIM 1024

#define M_TILE 128
#define N_TILE 128
#define BK 64
#define KSPLIT 2
#define KCHUNK (I_DIM / KSPLIT)  // 1024
#define NSTEP (KCHUNK / BK)      // 16

typedef __bf16 bf16x8 __attribute__((ext_vector_type(8)));
typedef float f32x4 __attribute__((ext_vector_type(4)));

__device__ inline void load_lds16(const void* g, void* l) {
    // lane i's 16B land at (wave-uniform) l + i*16; global src is per-lane
    __builtin_amdgcn_global_load_lds(
        (const __attribute__((address_space(1))) void*)g,
        (__attribute__((address_space(3))) void*)l, 16, 0, 0);
}

// Fused prep, one dispatch:
//  blocks [0,2048):    w [E][K][N] fp32 -> wT [E][N][K] bf16 (128k x 64n tiles)
//  blocks [2048,4096): x fp32 -> xB bf16 streaming convert
//  blocks [4096,5120): zero out
//  block  5120:        routing (softmax top-2 + per-expert rowlists), single
//                      block -> LDS-atomic positions, no global cnt pre-zero
__global__ __launch_bounds__(256) void prep_kernel(
    const float* __restrict__ w, const float* __restrict__ x,
    const float* __restrict__ logits,
    __bf16* __restrict__ wT, __bf16* __restrict__ xB,
    float* __restrict__ out, float* __restrict__ topk_w,
    int* __restrict__ cnt, int* __restrict__ rowlist) {
    const int b = blockIdx.x;
    const int t = threadIdx.x;
    if (b < 2048) {
        __shared__ float tile[128 * 65];   // pitch 65: col reads <=4-way
        const int e = b >> 8;              // 256 blocks/expert = 16 ktiles*16 ntiles
        const int k0 = ((b >> 4) & 15) * 128;
        const int n0 = (b & 15) * 64;
        const float* ws = w + (size_t)e * (I_DIM * H_DIM) + (size_t)k0 * H_DIM + n0;
#pragma unroll
        for (int i = 0; i < 8; ++i) {
            int flat = i * 256 + t;
            int k = flat >> 4, nq = (flat & 15) * 4;   // 16 lanes = 256B contiguous
            f32x4 v = *(const f32x4*)(ws + (size_t)k * H_DIM + nq);
            float* d = &tile[k * 65 + nq];
            d[0] = v.x; d[1] = v.y; d[2] = v.z; d[3] = v.w;
        }
        __syncthreads();
        __bf16* wd = wT + (size_t)e * (H_DIM * I_DIM) + (size_t)n0 * I_DIM + k0;
#pragma unroll
        for (int j = 0; j < 4; ++j) {
            int flat = j * 256 + t;
            int n = flat >> 4, kc = (flat & 15) * 8;   // 16 lanes = 256B contiguous
            bf16x8 o;
#pragma unroll
            for (int q = 0; q < 8; ++q) o[q] = (__bf16)tile[(kc + q) * 65 + n];
            *(bf16x8*)(wd + (size_t)n * I_DIM + kc) = o;
        }
    } else if (b < 4096) {
        // 2048 blocks * 256 thr * 16 elems = 8M = ROWS*I_DIM
        size_t base = ((size_t)(b - 2048) * 256 + t) * 16;
        const f32x4* xs = (const f32x4*)(x + base);
        f32x4 v0 = xs[0], v1 = xs[1], v2 = xs[2], v3 = xs[3];
        bf16x8 o0 = { (__bf16)v0.x, (__bf16)v0.y, (__bf16)v0.z, (__bf16)v0.w,
                      (__bf16)v1.x, (__bf16)v1.y, (__bf16)v1.z, (__bf16)v1.w };
        bf16x8 o1 = { (__bf16)v2.x, (__bf16)v2.y, (__bf16)v2.z, (__bf16)v2.w,
                      (__bf16)v3.x, (__bf16)v3.y, (__bf16)v3.z, (__bf16)v3.w };
        *(bf16x8*)(xB + base) = o0;
        *(bf16x8*)(xB + base + 8) = o1;
    } else if (b < 5120) {
        // 1024 blocks * 256 thr * 8 floats = 2M = T_TOKENS*H_DIM
        size_t idx = (size_t)(b - 4096) * 256 + t;
        f32x4 z = (f32x4){0.f, 0.f, 0.f, 0.f};
        ((f32x4*)out)[2 * idx] = z;
        ((f32x4*)out)[2 * idx + 1] = z;
    } else {
        // routing: 2048 tokens, 8 per thread; strict '>' keeps lower index first
        // on ties, matching jax.lax.top_k
        __shared__ int lcnt[N_EXPERTS];
        if (t < N_EXPERTS) lcnt[t] = 0;
        __syncthreads();
#pragma unroll
        for (int i = 0; i < 8; ++i) {
            int tok = i * 256 + t;
            float l[8];
#pragma unroll
            for (int e = 0; e < 8; ++e) l[e] = logits[tok * 8 + e];
            float mx = l[0];
#pragma unroll
            for (int e = 1; e < 8; ++e) mx = fmaxf(mx, l[e]);
            float s = 0.f;
#pragma unroll
            for (int e = 0; e < 8; ++e) { l[e] = expf(l[e] - mx); s += l[e]; }
            float inv = 1.f / s;
            float v0 = -1.f, v1 = -1.f; int i0 = 0, i1 = 0;
#pragma unroll
            for (int e = 0; e < 8; ++e) {
                float p = l[e] * inv;
                if (p > v0)      { v1 = v0; i1 = i0; v0 = p; i0 = e; }
                else if (p > v1) { v1 = p; i1 = e; }
            }
            topk_w[2 * tok]     = v0;
            topk_w[2 * tok + 1] = v1;
            int p0 = atomicAdd(&lcnt[i0], 1); rowlist[i0 * ROWS + p0] = 2 * tok;
            int p1 = atomicAdd(&lcnt[i1], 1); rowlist[i1 * ROWS + p1] = 2 * tok + 1;
        }
        __syncthreads();
        if (t < N_EXPERTS) cnt[t] = lcnt[t];
    }
}

// Grouped expert GEMM, 128x128 block tile, BK=64, 2-phase double-buffered
// pipeline (catalog T3-minimum): STAGE(next buf) issued BEFORE compute of
// current buf; single __syncthreads per K-step whose vmcnt(0) drains the
// prefetch -> HBM/L2 latency hides under the 128-MFMA compute phase.
// 4 waves, 64x64 per wave (4x4 frags of 16x16x32) -> 32 FLOP/LDS-byte.
// XOR-chunk swizzle (rule 21): linear LDS dest + inverse-swizzled global
// source chunk + same XOR on fragment-read address (proven conflict-free).
__global__ __launch_bounds__(256, 2) void gemm_kernel(
    const __bf16* __restrict__ xB, const __bf16* __restrict__ wT,
    const int* __restrict__ cnt, const int* __restrict__ rowlist,
    const float* __restrict__ topk_w, float* __restrict__ out) {
    const int e = blockIdx.y;
    const int cnt_e = cnt[e];
    const int m0 = blockIdx.z * M_TILE;
    if (m0 >= cnt_e) return;
    const int ntile = blockIdx.x & 7;
    const int khalf = blockIdx.x >> 3;
    const int n0 = ntile * N_TILE;
    const int tid = threadIdx.x;
    const int lane = tid & 63;
    const int wave = tid >> 6;
    const int wm = wave & 1, wn = wave >> 1;

    __shared__ __bf16 As[2][M_TILE * BK];   // 2 x 16 KB
    __shared__ __bf16 Bs[2][N_TILE * BK];   // 2 x 16 KB

    const int* rl = rowlist + e * ROWS;

    const int lc = lane & 7;    // 16B chunk within a 128B row
    const int lr = lane >> 3;   // row within an 8-row DMA group
    const int cg = lc ^ lr;     // inverse-swizzled global chunk (row&7 == lr)

    // A: 4 DMA/wave cover rows 32w..32w+31 (gathered via rowlist)
    const __bf16* asrc[4];
#pragma unroll
    for (int i = 0; i < 4; ++i) {
        int gm = m0 + 32 * wave + 8 * i + lr;
        if (gm >= cnt_e) gm = cnt_e - 1;   // dup row, dropped in epilogue
        asrc[i] = xB + (size_t)rl[gm] * I_DIM + khalf * KCHUNK + cg * 8;
    }
    // B: 4 DMA/wave cover n-rows 32w..32w+31
    const __bf16* wTe = wT + (size_t)e * (H_DIM * I_DIM);
    const __bf16* bsrc = wTe + (size_t)(n0 + 32 * wave + lr) * I_DIM
                             + khalf * KCHUNK + cg * 8;

    // fragment-read offsets (elements), swizzled with the same XOR:
    // row = {wm|wn}*64 + f*16 + lm  ->  (row&7) == (lm&7)
    const int lm = lane & 15, lg = lane >> 4, sw = lm & 7;
    int offA[2][4], offB[2][4];
#pragma unroll
    for (int s = 0; s < 2; ++s) {
        int cs = (((s * 4) + lg) ^ sw) * 8;
#pragma unroll
        for (int f = 0; f < 4; ++f) {
            offA[s][f] = (wm * 64 + f * 16 + lm) * BK + cs;
            offB[s][f] = (wn * 64 + f * 16 + lm) * BK + cs;
        }
    }

    f32x4 acc[4][4];
#pragma unroll
    for (int mt = 0; mt < 4; ++mt)
#pragma unroll
        for (int nt = 0; nt < 4; ++nt)
            acc[mt][nt] = (f32x4){0.f, 0.f, 0.f, 0.f};

    // prologue: stage buf0 with k-offset 0
#pragma unroll
    for (int i = 0; i < 4; ++i) {
        load_lds16(asrc[i], &As[0][(32 * wave + 8 * i) * BK]);
        load_lds16(bsrc + (size_t)(8 * i) * I_DIM, &Bs[0][(32 * wave + 8 * i) * BK]);
    }
    __syncthreads();   // vmcnt(0): buf0 ready

    for (int tstep = 0; tstep < NSTEP; ++tstep) {
        const int cur = tstep & 1;
        if (tstep + 1 < NSTEP) {
            const int koff = (tstep + 1) * BK;
#pragma unroll
            for (int i = 0; i < 4; ++i) {
                load_lds16(asrc[i] + koff, &As[cur ^ 1][(32 * wave + 8 * i) * BK]);
                load_lds16(bsrc + (size_t)(8 * i) * I_DIM + koff,
                           &Bs[cur ^ 1][(32 * wave + 8 * i) * BK]);
            }
        }
        const __bf16* Ab = As[cur];
        const __bf16* Bb = Bs[cur];
#pragma unroll
        for (int s = 0; s < 2; ++s) {
            bf16x8 af[4], bfr[4];
#pragma unroll
            for (int f = 0; f < 4; ++f) af[f] = *(const bf16x8*)&Ab[offA[s][f]];
#pragma unroll
            for (int f = 0; f < 4; ++f) bfr[f] = *(const bf16x8*)&Bb[offB[s][f]];
#pragma unroll
            for (int mt = 0; mt < 4; ++mt)
#pragma unroll
                for (int nt = 0; nt < 4; ++nt)
                    acc[mt][nt] = __builtin_amdgcn_mfma_f32_16x16x32_bf16(
                        af[mt], bfr[nt], acc[mt][nt], 0, 0, 0);
        }
        __syncthreads();   // drains next-buf prefetch (vmcnt 0) + lgkm reads
    }

    // epilogue: C/D col=lane&15, row=(lane>>4)*4+reg; scale by topk weight,
    // atomicAdd into out[token] (covers topk-sum and K-split sum)
    const int lq = lane >> 4, ln = lane & 15;
#pragma unroll
    for (int mt = 0; mt < 4; ++mt) {
#pragma unroll
        for (int j = 0; j < 4; ++j) {
            int gm = m0 + wm * 64 + mt * 16 + lq * 4 + j;
            if (gm < cnt_e) {
                int row = rl[gm];
                float tw = topk_w[row];
                float* orow = out + (size_t)(row >> 1) * H_DIM + n0 + wn * 64 + ln;
#pragma unroll
                for (int nt = 0; nt < 4; ++nt)
                    atomicAdd(&orow[nt * 16], acc[mt][nt][j] * tw);
            }
        }
    }
}

extern "C" void kernel_launch(void* const* d_in, const int* in_sizes, int n_in,
                              void* d_out, int out_size, void* d_ws, size_t ws_size,
                              hipStream_t stream) {
    const float* x      = (const float*)d_in[0];  // [ROWS, I_DIM] fp32
    const float* w      = (const float*)d_in[1];  // [E, I_DIM, H_DIM] fp32
    const float* logits = (const float*)d_in[2];  // [T, E] fp32
    float* out = (float*)d_out;                   // [T, H_DIM] fp32

    char* ws = (char*)d_ws;
    float*  topk_w  = (float*)ws;                                      // 16 KB
    int*    cnt     = (int*)(ws + 16384);                              // 128 B
    int*    rowlist = (int*)(ws + 16384 + 128);                        // 128 KB
    __bf16* wT      = (__bf16*)(ws + 16384 + 128 + 131072);            // 32 MB [E][H][I]
    __bf16* xB      = (__bf16*)(ws + 16384 + 128 + 131072 + 33554432); // 16 MB [ROWS][I]

    // prep: w transpose+convert (2048) + x convert (2048) + out zero (1024)
    //       + routing (1 block)
    prep_kernel<<<5121, 256, 0, stream>>>(w, x, logits, wT, xB, out, topk_w, cnt, rowlist);
    // x = ntile+khalf (all active), y = expert, z = m-tile (early-exit tail)
    gemm_kernel<<<dim3((H_DIM / N_TILE) * KSPLIT, N_EXPERTS, ROWS / M_TILE), 256, 0, stream>>>(
        xB, wT, cnt, rowlist, topk_w, out);
}

// Round 3
// 167.643 us; speedup vs baseline: 1.1883x; 1.1883x over previous
//
#include <hip/hip_runtime.h>

#define T_TOKENS 2048
#define N_EXPERTS 8
#define ROWS (T_TOKENS * 2)      // T * TOPK
#define I_DIM 2048
#define H_DIM 1024

#define M_TILE 64
#define N_TILE 128
#define BK 64
#define NSTEP (I_DIM / BK)       // 32, full K per block (no K-split)

typedef __bf16 bf16x8 __attribute__((ext_vector_type(8)));
typedef float f32x4 __attribute__((ext_vector_type(4)));

__device__ inline void load_lds16(const void* g, void* l) {
    // lane i's 16B land at (wave-uniform) l + i*16; global src is per-lane
    __builtin_amdgcn_global_load_lds(
        (const __attribute__((address_space(1))) void*)g,
        (__attribute__((address_space(3))) void*)l, 16, 0, 0);
}

// Fused prep, one dispatch:
//  block  0:           routing (softmax top-2 + per-expert rowlists, LDS-atomic
//                      positions, no global cnt pre-zero) -- first so it starts early
//  blocks [1,2049):    w [E][K][N] fp32 -> wT [E][N][K] bf16 (128k x 64n tiles)
//  blocks [2049,4097): x fp32 -> xB bf16 streaming convert
//  blocks [4097,5121): zero out
__global__ __launch_bounds__(256) void prep_kernel(
    const float* __restrict__ w, const float* __restrict__ x,
    const float* __restrict__ logits,
    __bf16* __restrict__ wT, __bf16* __restrict__ xB,
    float* __restrict__ out, float* __restrict__ topk_w,
    int* __restrict__ cnt, int* __restrict__ rowlist) {
    const int b = blockIdx.x;
    const int t = threadIdx.x;
    if (b == 0) {
        // routing: 2048 tokens, 8 per thread; strict '>' keeps lower index first
        // on ties, matching jax.lax.top_k
        __shared__ int lcnt[N_EXPERTS];
        if (t < N_EXPERTS) lcnt[t] = 0;
        __syncthreads();
#pragma unroll
        for (int i = 0; i < 8; ++i) {
            int tok = i * 256 + t;
            float l[8];
#pragma unroll
            for (int e = 0; e < 8; ++e) l[e] = logits[tok * 8 + e];
            float mx = l[0];
#pragma unroll
            for (int e = 1; e < 8; ++e) mx = fmaxf(mx, l[e]);
            float s = 0.f;
#pragma unroll
            for (int e = 0; e < 8; ++e) { l[e] = expf(l[e] - mx); s += l[e]; }
            float inv = 1.f / s;
            float v0 = -1.f, v1 = -1.f; int i0 = 0, i1 = 0;
#pragma unroll
            for (int e = 0; e < 8; ++e) {
                float p = l[e] * inv;
                if (p > v0)      { v1 = v0; i1 = i0; v0 = p; i0 = e; }
                else if (p > v1) { v1 = p; i1 = e; }
            }
            topk_w[2 * tok]     = v0;
            topk_w[2 * tok + 1] = v1;
            int p0 = atomicAdd(&lcnt[i0], 1); rowlist[i0 * ROWS + p0] = 2 * tok;
            int p1 = atomicAdd(&lcnt[i1], 1); rowlist[i1 * ROWS + p1] = 2 * tok + 1;
        }
        __syncthreads();
        if (t < N_EXPERTS) cnt[t] = lcnt[t];
    } else if (b < 2049) {
        const int bb = b - 1;
        __shared__ float tile[128 * 65];   // pitch 65: col reads <=4-way
        const int e = bb >> 8;             // 256 blocks/expert = 16 ktiles*16 ntiles
        const int k0 = ((bb >> 4) & 15) * 128;
        const int n0 = (bb & 15) * 64;
        const float* ws = w + (size_t)e * (I_DIM * H_DIM) + (size_t)k0 * H_DIM + n0;
#pragma unroll
        for (int i = 0; i < 8; ++i) {
            int flat = i * 256 + t;
            int k = flat >> 4, nq = (flat & 15) * 4;   // 16 lanes = 256B contiguous
            f32x4 v = *(const f32x4*)(ws + (size_t)k * H_DIM + nq);
            float* d = &tile[k * 65 + nq];
            d[0] = v.x; d[1] = v.y; d[2] = v.z; d[3] = v.w;
        }
        __syncthreads();
        __bf16* wd = wT + (size_t)e * (H_DIM * I_DIM) + (size_t)n0 * I_DIM + k0;
#pragma unroll
        for (int j = 0; j < 4; ++j) {
            int flat = j * 256 + t;
            int n = flat >> 4, kc = (flat & 15) * 8;   // 16 lanes = 256B contiguous
            bf16x8 o;
#pragma unroll
            for (int q = 0; q < 8; ++q) o[q] = (__bf16)tile[(kc + q) * 65 + n];
            *(bf16x8*)(wd + (size_t)n * I_DIM + kc) = o;
        }
    } else if (b < 4097) {
        // 2048 blocks * 256 thr * 16 elems = 8M = ROWS*I_DIM
        size_t base = ((size_t)(b - 2049) * 256 + t) * 16;
        const f32x4* xs = (const f32x4*)(x + base);
        f32x4 v0 = xs[0], v1 = xs[1], v2 = xs[2], v3 = xs[3];
        bf16x8 o0 = { (__bf16)v0.x, (__bf16)v0.y, (__bf16)v0.z, (__bf16)v0.w,
                      (__bf16)v1.x, (__bf16)v1.y, (__bf16)v1.z, (__bf16)v1.w };
        bf16x8 o1 = { (__bf16)v2.x, (__bf16)v2.y, (__bf16)v2.z, (__bf16)v2.w,
                      (__bf16)v3.x, (__bf16)v3.y, (__bf16)v3.z, (__bf16)v3.w };
        *(bf16x8*)(xB + base) = o0;
        *(bf16x8*)(xB + base + 8) = o1;
    } else {
        // 1024 blocks * 256 thr * 8 floats = 2M = T_TOKENS*H_DIM
        size_t idx = (size_t)(b - 4097) * 256 + t;
        f32x4 z = (f32x4){0.f, 0.f, 0.f, 0.f};
        ((f32x4*)out)[2 * idx] = z;
        ((f32x4*)out)[2 * idx + 1] = z;
    }
}

// Grouped expert GEMM, 64x128 tile, BK=64, full K=2048 (32 steps).
// TRUE 2-phase pipeline (catalog T3+T4): per step
//   STAGE(next buf, 6 DMAs) -> s_waitcnt vmcnt(6) -> raw s_barrier
//   -> 16 MFMAs on current buf -> raw s_barrier
// Counted vmcnt keeps the 6 prefetch DMAs in flight ACROSS the barrier
// (round-2's __syncthreads drained them -> no overlap; this fixes it).
// vmcnt(0) only on the final step. 48 KB LDS -> 3 blocks/CU (12 waves).
// XOR-chunk swizzle (rule 21): linear LDS dest + inverse-swizzled global
// source chunk + same XOR on fragment-read address (proven 0 conflicts).
__global__ __launch_bounds__(256, 3) void gemm_kernel(
    const __bf16* __restrict__ xB, const __bf16* __restrict__ wT,
    const int* __restrict__ cnt, const int* __restrict__ rowlist,
    const float* __restrict__ topk_w, float* __restrict__ out) {
    const int e = blockIdx.y;
    const int cnt_e = cnt[e];
    const int m0 = blockIdx.z * M_TILE;
    if (m0 >= cnt_e) return;
    const int n0 = blockIdx.x * N_TILE;   // bid%8 = ntile -> XCD-pinned n-strip
    const int tid = threadIdx.x;
    const int lane = tid & 63;
    const int wave = tid >> 6;
    const int wm = wave & 1, wn = wave >> 1;

    __shared__ __bf16 As[2][M_TILE * BK];   // 2 x 8 KB
    __shared__ __bf16 Bs[2][N_TILE * BK];   // 2 x 16 KB

    const int* rl = rowlist + e * ROWS;

    const int lc = lane & 7;    // 16B chunk within a 128B row
    const int lr = lane >> 3;   // row within an 8-row DMA group
    const int cg = lc ^ lr;     // inverse-swizzled global chunk (row&7 == lr)

    // A: 2 DMA/wave cover rows 16w..16w+15 (gathered via rowlist)
    int gm0 = m0 + 16 * wave + lr;
    int gm1 = gm0 + 8;
    if (gm0 >= cnt_e) gm0 = cnt_e - 1;   // dup row, dropped in epilogue
    if (gm1 >= cnt_e) gm1 = cnt_e - 1;
    const __bf16* asrc0 = xB + (size_t)rl[gm0] * I_DIM + cg * 8;
    const __bf16* asrc1 = xB + (size_t)rl[gm1] * I_DIM + cg * 8;
    // B: 4 DMA/wave cover n-rows 32w..32w+31
    const __bf16* wTe = wT + (size_t)e * (H_DIM * I_DIM);
    const __bf16* bsrc = wTe + (size_t)(n0 + 32 * wave + lr) * I_DIM + cg * 8;

    // fragment-read offsets (elements), swizzled with the same XOR:
    // row = wm*32|wn*64 + f*16 + lm  ->  (row&7) == (lm&7)
    const int lm = lane & 15, lg = lane >> 4, sw = lm & 7;
    int offA[2][2], offB[2][4];
#pragma unroll
    for (int s = 0; s < 2; ++s) {
        int cs = (((s * 4) + lg) ^ sw) * 8;
#pragma unroll
        for (int mt = 0; mt < 2; ++mt)
            offA[s][mt] = (wm * 32 + mt * 16 + lm) * BK + cs;
#pragma unroll
        for (int nt = 0; nt < 4; ++nt)
            offB[s][nt] = (wn * 64 + nt * 16 + lm) * BK + cs;
    }

    f32x4 acc[2][4];
#pragma unroll
    for (int mt = 0; mt < 2; ++mt)
#pragma unroll
        for (int nt = 0; nt < 4; ++nt)
            acc[mt][nt] = (f32x4){0.f, 0.f, 0.f, 0.f};

#define STAGE(buf, koff)                                                  \
    do {                                                                  \
        load_lds16(asrc0 + (koff), &As[buf][wave * 1024]);                \
        load_lds16(asrc1 + (koff), &As[buf][wave * 1024 + 512]);          \
        load_lds16(bsrc + (koff),               &Bs[buf][wave * 2048]);   \
        load_lds16(bsrc +  8 * I_DIM + (koff),  &Bs[buf][wave * 2048 + 512]);  \
        load_lds16(bsrc + 16 * I_DIM + (koff),  &Bs[buf][wave * 2048 + 1024]); \
        load_lds16(bsrc + 24 * I_DIM + (koff),  &Bs[buf][wave * 2048 + 1536]); \
    } while (0)

    STAGE(0, 0);   // prologue: 6 DMAs in flight for step 0

    for (int t = 0; t < NSTEP; ++t) {
        const int cur = t & 1;
        if (t + 1 < NSTEP) {
            STAGE(cur ^ 1, (t + 1) * BK);                       // 12 in flight
            asm volatile("s_waitcnt vmcnt(6)" ::: "memory");    // step-t's 6 done
        } else {
            asm volatile("s_waitcnt vmcnt(0)" ::: "memory");    // drain last tile
        }
        __builtin_amdgcn_s_barrier();       // all waves: buf[cur] fully written
        asm volatile("" ::: "memory");      // keep ds_reads below the barrier

        const __bf16* Ab = As[cur];
        const __bf16* Bb = Bs[cur];
#pragma unroll
        for (int s = 0; s < 2; ++s) {
            bf16x8 af[2], bfr[4];
#pragma unroll
            for (int f = 0; f < 2; ++f) af[f] = *(const bf16x8*)&Ab[offA[s][f]];
#pragma unroll
            for (int f = 0; f < 4; ++f) bfr[f] = *(const bf16x8*)&Bb[offB[s][f]];
#pragma unroll
            for (int mt = 0; mt < 2; ++mt)
#pragma unroll
                for (int nt = 0; nt < 4; ++nt)
                    acc[mt][nt] = __builtin_amdgcn_mfma_f32_16x16x32_bf16(
                        af[mt], bfr[nt], acc[mt][nt], 0, 0, 0);
        }
        asm volatile("" ::: "memory");      // keep ds_reads above the barrier
        __builtin_amdgcn_s_barrier();       // all waves done reading buf[cur]
    }
#undef STAGE

    // epilogue: C/D col=lane&15, row=(lane>>4)*4+reg; scale by topk weight,
    // atomicAdd into out[token] (covers the topk-sum across experts)
    const int lq = lane >> 4, ln = lane & 15;
#pragma unroll
    for (int mt = 0; mt < 2; ++mt) {
#pragma unroll
        for (int j = 0; j < 4; ++j) {
            int gm = m0 + wm * 32 + mt * 16 + lq * 4 + j;
            if (gm < cnt_e) {
                int row = rl[gm];
                float tw = topk_w[row];
                float* orow = out + (size_t)(row >> 1) * H_DIM + n0 + wn * 64 + ln;
#pragma unroll
                for (int nt = 0; nt < 4; ++nt)
                    atomicAdd(&orow[nt * 16], acc[mt][nt][j] * tw);
            }
        }
    }
}

extern "C" void kernel_launch(void* const* d_in, const int* in_sizes, int n_in,
                              void* d_out, int out_size, void* d_ws, size_t ws_size,
                              hipStream_t stream) {
    const float* x      = (const float*)d_in[0];  // [ROWS, I_DIM] fp32
    const float* w      = (const float*)d_in[1];  // [E, I_DIM, H_DIM] fp32
    const float* logits = (const float*)d_in[2];  // [T, E] fp32
    float* out = (float*)d_out;                   // [T, H_DIM] fp32

    char* ws = (char*)d_ws;
    float*  topk_w  = (float*)ws;                                      // 16 KB
    int*    cnt     = (int*)(ws + 16384);                              // 128 B
    int*    rowlist = (int*)(ws + 16384 + 128);                        // 128 KB
    __bf16* wT      = (__bf16*)(ws + 16384 + 128 + 131072);            // 32 MB [E][H][I]
    __bf16* xB      = (__bf16*)(ws + 16384 + 128 + 131072 + 33554432); // 16 MB [ROWS][I]

    // prep: routing (1) + w transpose+convert (2048) + x convert (2048)
    //       + out zero (1024)
    prep_kernel<<<5121, 256, 0, stream>>>(w, x, logits, wT, xB, out, topk_w, cnt, rowlist);
    // x = ntile (XCD-pinned), y = expert, z = m-tile (early-exit tail)
    gemm_kernel<<<dim3(H_DIM / N_TILE, N_EXPERTS, ROWS / M_TILE), 256, 0, stream>>>(
        xB, wT, cnt, rowlist, topk_w, out);
}

// Round 5
// 166.696 us; speedup vs baseline: 1.1951x; 1.0057x over previous
//
#include <hip/hip_runtime.h>

#define T_TOKENS 2048
#define N_EXPERTS 8
#define ROWS (T_TOKENS * 2)      // T * TOPK
#define I_DIM 2048
#define H_DIM 1024

#define M_TILE 64
#define N_TILE 128
#define BK 64
#define NSTEP (I_DIM / BK)       // 32, full K per block (no K-split)

#define TP 68                    // transpose tile pitch (words): mult of 4 keeps
                                 // every u32x4 read 16B-aligned (65 was the bug)

typedef __bf16 bf16x8 __attribute__((ext_vector_type(8)));
typedef float f32x4 __attribute__((ext_vector_type(4)));
typedef unsigned int u32;
typedef u32 u32x4 __attribute__((ext_vector_type(4)));

__device__ inline void load_lds16(const void* g, void* l) {
    // lane i's 16B land at (wave-uniform) l + i*16; global src is per-lane
    __builtin_amdgcn_global_load_lds(
        (const __attribute__((address_space(1))) void*)g,
        (__attribute__((address_space(3))) void*)l, 16, 0, 0);
}

__device__ inline u32 pack2(float a, float b) {
    // bf16(a) in low half, bf16(b) in high half == bf16[2k],bf16[2k+1] in memory
    union { __bf16 h[2]; u32 w; } u;
    u.h[0] = (__bf16)a; u.h[1] = (__bf16)b;
    return u.w;
}

// Fused prep, one dispatch:
//  block  0:           routing (softmax top-2 + per-expert rowlists, LDS-atomic
//                      positions, no global cnt pre-zero)
//  blocks [1,2049):    w [E][K][N] fp32 -> wT [E][N][K] bf16, 128k x 64n tiles.
//                      Convert-before-LDS: k-pair bf16 words in [64n][TP] tile
//                      (17.4 KB -> 8 blocks/CU), all LDS ops vector, <=4-way.
//  blocks [2049,4097): x fp32 -> xB bf16 streaming convert
//  blocks [4097,5121): zero out
__global__ __launch_bounds__(256) void prep_kernel(
    const float* __restrict__ w, const float* __restrict__ x,
    const float* __restrict__ logits,
    __bf16* __restrict__ wT, __bf16* __restrict__ xB,
    float* __restrict__ out, float* __restrict__ topk_w,
    int* __restrict__ cnt, int* __restrict__ rowlist) {
    const int b = blockIdx.x;
    const int t = threadIdx.x;
    if (b == 0) {
        // routing: 2048 tokens, 8 per thread; strict '>' keeps lower index first
        // on ties, matching jax.lax.top_k
        __shared__ int lcnt[N_EXPERTS];
        if (t < N_EXPERTS) lcnt[t] = 0;
        __syncthreads();
#pragma unroll
        for (int i = 0; i < 8; ++i) {
            int tok = i * 256 + t;
            float l[8];
#pragma unroll
            for (int e = 0; e < 8; ++e) l[e] = logits[tok * 8 + e];
            float mx = l[0];
#pragma unroll
            for (int e = 1; e < 8; ++e) mx = fmaxf(mx, l[e]);
            float s = 0.f;
#pragma unroll
            for (int e = 0; e < 8; ++e) { l[e] = expf(l[e] - mx); s += l[e]; }
            float inv = 1.f / s;
            float v0 = -1.f, v1 = -1.f; int i0 = 0, i1 = 0;
#pragma unroll
            for (int e = 0; e < 8; ++e) {
                float p = l[e] * inv;
                if (p > v0)      { v1 = v0; i1 = i0; v0 = p; i0 = e; }
                else if (p > v1) { v1 = p; i1 = e; }
            }
            topk_w[2 * tok]     = v0;
            topk_w[2 * tok + 1] = v1;
            int p0 = atomicAdd(&lcnt[i0], 1); rowlist[i0 * ROWS + p0] = 2 * tok;
            int p1 = atomicAdd(&lcnt[i1], 1); rowlist[i1 * ROWS + p1] = 2 * tok + 1;
        }
        __syncthreads();
        if (t < N_EXPERTS) cnt[t] = lcnt[t];
    } else if (b < 2049) {
        const int bb = b - 1;
        // tile[n][kpair-word], pitch TP=68 (16B-aligned b128 reads; <=4-way writes)
        __shared__ u32 tile[64 * TP];      // 17.4 KB
        const int e = bb >> 8;             // 256 blocks/expert = 16 ktiles*16 ntiles
        const int k0 = ((bb >> 4) & 15) * 128;
        const int n0 = (bb & 15) * 64;
        const float* ws = w + (size_t)e * (I_DIM * H_DIM) + (size_t)k0 * H_DIM + n0;
#pragma unroll
        for (int i = 0; i < 4; ++i) {
            int kp = i * 16 + (t >> 4);        // k-pair index in [0,64)
            int nq = (t & 15) * 4;             // 16 lanes = 256B contiguous
            const float* p = ws + (size_t)(2 * kp) * H_DIM + nq;
            f32x4 v0 = *(const f32x4*)p;
            f32x4 v1 = *(const f32x4*)(p + H_DIM);
            tile[(nq + 0) * TP + kp] = pack2(v0.x, v1.x);
            tile[(nq + 1) * TP + kp] = pack2(v0.y, v1.y);
            tile[(nq + 2) * TP + kp] = pack2(v0.z, v1.z);
            tile[(nq + 3) * TP + kp] = pack2(v0.w, v1.w);
        }
        __syncthreads();
        __bf16* wd = wT + (size_t)e * (H_DIM * I_DIM) + (size_t)n0 * I_DIM + k0;
#pragma unroll
        for (int i = 0; i < 4; ++i) {
            int n = i * 16 + (t >> 4);
            int c = t & 15;                    // 16 lanes = 256B contiguous
            u32x4 r = *(const u32x4*)&tile[n * TP + 4 * c];   // 16B-aligned (TP%4==0)
            *(u32x4*)(wd + (size_t)n * I_DIM + 8 * c) = r;
        }
    } else if (b < 4097) {
        // 2048 blocks * 256 thr * 16 elems = 8M = ROWS*I_DIM
        size_t base = ((size_t)(b - 2049) * 256 + t) * 16;
        const f32x4* xs = (const f32x4*)(x + base);
        f32x4 v0 = xs[0], v1 = xs[1], v2 = xs[2], v3 = xs[3];
        bf16x8 o0 = { (__bf16)v0.x, (__bf16)v0.y, (__bf16)v0.z, (__bf16)v0.w,
                      (__bf16)v1.x, (__bf16)v1.y, (__bf16)v1.z, (__bf16)v1.w };
        bf16x8 o1 = { (__bf16)v2.x, (__bf16)v2.y, (__bf16)v2.z, (__bf16)v2.w,
                      (__bf16)v3.x, (__bf16)v3.y, (__bf16)v3.z, (__bf16)v3.w };
        *(bf16x8*)(xB + base) = o0;
        *(bf16x8*)(xB + base + 8) = o1;
    } else {
        // 1024 blocks * 256 thr * 8 floats = 2M = T_TOKENS*H_DIM
        size_t idx = (size_t)(b - 4097) * 256 + t;
        f32x4 z = (f32x4){0.f, 0.f, 0.f, 0.f};
        ((f32x4*)out)[2 * idx] = z;
        ((f32x4*)out)[2 * idx + 1] = z;
    }
}

// Grouped expert GEMM, 64x128 tile, BK=64, full K=2048 (32 steps).
// TRUE 2-phase pipeline (catalog T3+T4): per step
//   STAGE(next buf, 6 DMAs) -> s_waitcnt vmcnt(6) -> raw s_barrier
//   -> 16 MFMAs on current buf -> raw s_barrier
// Counted vmcnt keeps the 6 prefetch DMAs in flight ACROSS the barrier.
// vmcnt(0) only on the final step. 48 KB LDS -> 3 blocks/CU (12 waves).
// XOR-chunk swizzle (rule 21): linear LDS dest + inverse-swizzled global
// source chunk + same XOR on fragment-read address (proven 0 conflicts).
__global__ __launch_bounds__(256, 3) void gemm_kernel(
    const __bf16* __restrict__ xB, const __bf16* __restrict__ wT,
    const int* __restrict__ cnt, const int* __restrict__ rowlist,
    const float* __restrict__ topk_w, float* __restrict__ out) {
    const int e = blockIdx.y;
    const int cnt_e = cnt[e];
    const int m0 = blockIdx.z * M_TILE;
    if (m0 >= cnt_e) return;
    const int n0 = blockIdx.x * N_TILE;   // bid%8 = ntile -> XCD-pinned n-strip
    const int tid = threadIdx.x;
    const int lane = tid & 63;
    const int wave = tid >> 6;
    const int wm = wave & 1, wn = wave >> 1;

    __shared__ __bf16 As[2][M_TILE * BK];   // 2 x 8 KB
    __shared__ __bf16 Bs[2][N_TILE * BK];   // 2 x 16 KB

    const int* rl = rowlist + e * ROWS;

    const int lc = lane & 7;    // 16B chunk within a 128B row
    const int lr = lane >> 3;   // row within an 8-row DMA group
    const int cg = lc ^ lr;     // inverse-swizzled global chunk (row&7 == lr)

    // A: 2 DMA/wave cover rows 16w..16w+15 (gathered via rowlist)
    int gm0 = m0 + 16 * wave + lr;
    int gm1 = gm0 + 8;
    if (gm0 >= cnt_e) gm0 = cnt_e - 1;   // dup row, dropped in epilogue
    if (gm1 >= cnt_e) gm1 = cnt_e - 1;
    const __bf16* asrc0 = xB + (size_t)rl[gm0] * I_DIM + cg * 8;
    const __bf16* asrc1 = xB + (size_t)rl[gm1] * I_DIM + cg * 8;
    // B: 4 DMA/wave cover n-rows 32w..32w+31
    const __bf16* wTe = wT + (size_t)e * (H_DIM * I_DIM);
    const __bf16* bsrc = wTe + (size_t)(n0 + 32 * wave + lr) * I_DIM + cg * 8;

    // fragment-read offsets (elements), swizzled with the same XOR:
    // row = wm*32|wn*64 + f*16 + lm  ->  (row&7) == (lm&7)
    const int lm = lane & 15, lg = lane >> 4, sw = lm & 7;
    int offA[2][2], offB[2][4];
#pragma unroll
    for (int s = 0; s < 2; ++s) {
        int cs = (((s * 4) + lg) ^ sw) * 8;
#pragma unroll
        for (int mt = 0; mt < 2; ++mt)
            offA[s][mt] = (wm * 32 + mt * 16 + lm) * BK + cs;
#pragma unroll
        for (int nt = 0; nt < 4; ++nt)
            offB[s][nt] = (wn * 64 + nt * 16 + lm) * BK + cs;
    }

    f32x4 acc[2][4];
#pragma unroll
    for (int mt = 0; mt < 2; ++mt)
#pragma unroll
        for (int nt = 0; nt < 4; ++nt)
            acc[mt][nt] = (f32x4){0.f, 0.f, 0.f, 0.f};

#define STAGE(buf, koff)                                                  \
    do {                                                                  \
        load_lds16(asrc0 + (koff), &As[buf][wave * 1024]);                \
        load_lds16(asrc1 + (koff), &As[buf][wave * 1024 + 512]);          \
        load_lds16(bsrc + (koff),               &Bs[buf][wave * 2048]);   \
        load_lds16(bsrc +  8 * I_DIM + (koff),  &Bs[buf][wave * 2048 + 512]);  \
        load_lds16(bsrc + 16 * I_DIM + (koff),  &Bs[buf][wave * 2048 + 1024]); \
        load_lds16(bsrc + 24 * I_DIM + (koff),  &Bs[buf][wave * 2048 + 1536]); \
    } while (0)

    STAGE(0, 0);   // prologue: 6 DMAs in flight for step 0

    for (int t = 0; t < NSTEP; ++t) {
        const int cur = t & 1;
        if (t + 1 < NSTEP) {
            STAGE(cur ^ 1, (t + 1) * BK);                       // 12 in flight
            asm volatile("s_waitcnt vmcnt(6)" ::: "memory");    // step-t's 6 done
        } else {
            asm volatile("s_waitcnt vmcnt(0)" ::: "memory");    // drain last tile
        }
        __builtin_amdgcn_s_barrier();       // all waves: buf[cur] fully written
        asm volatile("" ::: "memory");      // keep ds_reads below the barrier

        const __bf16* Ab = As[cur];
        const __bf16* Bb = Bs[cur];
#pragma unroll
        for (int s = 0; s < 2; ++s) {
            bf16x8 af[2], bfr[4];
#pragma unroll
            for (int f = 0; f < 2; ++f) af[f] = *(const bf16x8*)&Ab[offA[s][f]];
#pragma unroll
            for (int f = 0; f < 4; ++f) bfr[f] = *(const bf16x8*)&Bb[offB[s][f]];
#pragma unroll
            for (int mt = 0; mt < 2; ++mt)
#pragma unroll
                for (int nt = 0; nt < 4; ++nt)
                    acc[mt][nt] = __builtin_amdgcn_mfma_f32_16x16x32_bf16(
                        af[mt], bfr[nt], acc[mt][nt], 0, 0, 0);
        }
        asm volatile("" ::: "memory");      // keep ds_reads above the barrier
        __builtin_amdgcn_s_barrier();       // all waves done reading buf[cur]
    }
#undef STAGE

    // epilogue: C/D col=lane&15, row=(lane>>4)*4+reg; scale by topk weight,
    // atomicAdd into out[token] (covers the topk-sum across experts)
    const int lq = lane >> 4, ln = lane & 15;
#pragma unroll
    for (int mt = 0; mt < 2; ++mt) {
#pragma unroll
        for (int j = 0; j < 4; ++j) {
            int gm = m0 + wm * 32 + mt * 16 + lq * 4 + j;
            if (gm < cnt_e) {
                int row = rl[gm];
                float tw = topk_w[row];
                float* orow = out + (size_t)(row >> 1) * H_DIM + n0 + wn * 64 + ln;
#pragma unroll
                for (int nt = 0; nt < 4; ++nt)
                    atomicAdd(&orow[nt * 16], acc[mt][nt][j] * tw);
            }
        }
    }
}

extern "C" void kernel_launch(void* const* d_in, const int* in_sizes, int n_in,
                              void* d_out, int out_size, void* d_ws, size_t ws_size,
                              hipStream_t stream) {
    const float* x      = (const float*)d_in[0];  // [ROWS, I_DIM] fp32
    const float* w      = (const float*)d_in[1];  // [E, I_DIM, H_DIM] fp32
    const float* logits = (const float*)d_in[2];  // [T, E] fp32
    float* out = (float*)d_out;                   // [T, H_DIM] fp32

    char* ws = (char*)d_ws;
    float*  topk_w  = (float*)ws;                                      // 16 KB
    int*    cnt     = (int*)(ws + 16384);                              // 128 B
    int*    rowlist = (int*)(ws + 16384 + 128);                        // 128 KB
    __bf16* wT      = (__bf16*)(ws + 16384 + 128 + 131072);            // 32 MB [E][H][I]
    __bf16* xB      = (__bf16*)(ws + 16384 + 128 + 131072 + 33554432); // 16 MB [ROWS][I]

    // prep: routing (1) + w transpose+convert (2048) + x convert (2048)
    //       + out zero (1024)
    prep_kernel<<<5121, 256, 0, stream>>>(w, x, logits, wT, xB, out, topk_w, cnt, rowlist);
    // x = ntile (XCD-pinned), y = expert, z = m-tile (early-exit tail)
    gemm_kernel<<<dim3(H_DIM / N_TILE, N_EXPERTS, ROWS / M_TILE), 256, 0, stream>>>(
        xB, wT, cnt, rowlist, topk_w, out);
}

// Round 6
// 165.362 us; speedup vs baseline: 1.2047x; 1.0081x over previous
//
#include <hip/hip_runtime.h>

#define T_TOKENS 2048
#define N_EXPERTS 8
#define ROWS (T_TOKENS * 2)      // T * TOPK
#define I_DIM 2048
#define H_DIM 1024

#define M_TILE 64
#define N_TILE 128
#define BK 64
#define NSTEP (I_DIM / BK)       // 32, full K per block (no K-split)

#define TP 68                    // transpose tile pitch (words): mult of 4 keeps
                                 // every u32x4 read 16B-aligned

typedef __bf16 bf16x8 __attribute__((ext_vector_type(8)));
typedef float f32x4 __attribute__((ext_vector_type(4)));
typedef unsigned int u32;
typedef u32 u32x4 __attribute__((ext_vector_type(4)));

__device__ inline void load_lds16(const void* g, void* l) {
    // lane i's 16B land at (wave-uniform) l + i*16; global src is per-lane
    __builtin_amdgcn_global_load_lds(
        (const __attribute__((address_space(1))) void*)g,
        (__attribute__((address_space(3))) void*)l, 16, 0, 0);
}

__device__ inline u32 pack2(float a, float b) {
    // bf16(a) in low half, bf16(b) in high half == bf16[2k],bf16[2k+1] in memory
    union { __bf16 h[2]; u32 w; } u;
    u.h[0] = (__bf16)a; u.h[1] = (__bf16)b;
    return u.w;
}

// Fused prep, one dispatch:
//  block  0:           routing (softmax top-2 + per-expert rowlists, LDS-atomic
//                      positions, no global cnt pre-zero)
//  blocks [1,2049):    w [E][K][N] fp32 -> wT [E][N][K] bf16, 128k x 64n tiles.
//                      Convert-before-LDS: k-pair bf16 words in [64n][TP] tile
//                      (17.4 KB -> 8+ blocks/CU), all LDS ops vector, <=4-way.
//  blocks [2049,4097): x fp32 -> xB bf16 streaming convert
//  blocks [4097,5121): zero out
__global__ __launch_bounds__(256) void prep_kernel(
    const float* __restrict__ w, const float* __restrict__ x,
    const float* __restrict__ logits,
    __bf16* __restrict__ wT, __bf16* __restrict__ xB,
    float* __restrict__ out, float* __restrict__ topk_w,
    int* __restrict__ cnt, int* __restrict__ rowlist) {
    const int b = blockIdx.x;
    const int t = threadIdx.x;
    if (b == 0) {
        // routing: 2048 tokens, 8 per thread; strict '>' keeps lower index first
        // on ties, matching jax.lax.top_k
        __shared__ int lcnt[N_EXPERTS];
        if (t < N_EXPERTS) lcnt[t] = 0;
        __syncthreads();
#pragma unroll
        for (int i = 0; i < 8; ++i) {
            int tok = i * 256 + t;
            float l[8];
#pragma unroll
            for (int e = 0; e < 8; ++e) l[e] = logits[tok * 8 + e];
            float mx = l[0];
#pragma unroll
            for (int e = 1; e < 8; ++e) mx = fmaxf(mx, l[e]);
            float s = 0.f;
#pragma unroll
            for (int e = 0; e < 8; ++e) { l[e] = expf(l[e] - mx); s += l[e]; }
            float inv = 1.f / s;
            float v0 = -1.f, v1 = -1.f; int i0 = 0, i1 = 0;
#pragma unroll
            for (int e = 0; e < 8; ++e) {
                float p = l[e] * inv;
                if (p > v0)      { v1 = v0; i1 = i0; v0 = p; i0 = e; }
                else if (p > v1) { v1 = p; i1 = e; }
            }
            topk_w[2 * tok]     = v0;
            topk_w[2 * tok + 1] = v1;
            int p0 = atomicAdd(&lcnt[i0], 1); rowlist[i0 * ROWS + p0] = 2 * tok;
            int p1 = atomicAdd(&lcnt[i1], 1); rowlist[i1 * ROWS + p1] = 2 * tok + 1;
        }
        __syncthreads();
        if (t < N_EXPERTS) cnt[t] = lcnt[t];
    } else if (b < 2049) {
        const int bb = b - 1;
        // tile[n][kpair-word], pitch TP=68 (16B-aligned b128 reads; <=4-way writes)
        __shared__ u32 tile[64 * TP];      // 17.4 KB
        const int e = bb >> 8;             // 256 blocks/expert = 16 ktiles*16 ntiles
        const int k0 = ((bb >> 4) & 15) * 128;
        const int n0 = (bb & 15) * 64;
        const float* ws = w + (size_t)e * (I_DIM * H_DIM) + (size_t)k0 * H_DIM + n0;
#pragma unroll
        for (int i = 0; i < 4; ++i) {
            int kp = i * 16 + (t >> 4);        // k-pair index in [0,64)
            int nq = (t & 15) * 4;             // 16 lanes = 256B contiguous
            const float* p = ws + (size_t)(2 * kp) * H_DIM + nq;
            f32x4 v0 = *(const f32x4*)p;
            f32x4 v1 = *(const f32x4*)(p + H_DIM);
            tile[(nq + 0) * TP + kp] = pack2(v0.x, v1.x);
            tile[(nq + 1) * TP + kp] = pack2(v0.y, v1.y);
            tile[(nq + 2) * TP + kp] = pack2(v0.z, v1.z);
            tile[(nq + 3) * TP + kp] = pack2(v0.w, v1.w);
        }
        __syncthreads();
        __bf16* wd = wT + (size_t)e * (H_DIM * I_DIM) + (size_t)n0 * I_DIM + k0;
#pragma unroll
        for (int i = 0; i < 4; ++i) {
            int n = i * 16 + (t >> 4);
            int c = t & 15;                    // 16 lanes = 256B contiguous
            u32x4 r = *(const u32x4*)&tile[n * TP + 4 * c];   // 16B-aligned (TP%4==0)
            *(u32x4*)(wd + (size_t)n * I_DIM + 8 * c) = r;
        }
    } else if (b < 4097) {
        // 2048 blocks * 256 thr * 16 elems = 8M = ROWS*I_DIM
        size_t base = ((size_t)(b - 2049) * 256 + t) * 16;
        const f32x4* xs = (const f32x4*)(x + base);
        f32x4 v0 = xs[0], v1 = xs[1], v2 = xs[2], v3 = xs[3];
        bf16x8 o0 = { (__bf16)v0.x, (__bf16)v0.y, (__bf16)v0.z, (__bf16)v0.w,
                      (__bf16)v1.x, (__bf16)v1.y, (__bf16)v1.z, (__bf16)v1.w };
        bf16x8 o1 = { (__bf16)v2.x, (__bf16)v2.y, (__bf16)v2.z, (__bf16)v2.w,
                      (__bf16)v3.x, (__bf16)v3.y, (__bf16)v3.z, (__bf16)v3.w };
        *(bf16x8*)(xB + base) = o0;
        *(bf16x8*)(xB + base + 8) = o1;
    } else {
        // 1024 blocks * 256 thr * 8 floats = 2M = T_TOKENS*H_DIM
        size_t idx = (size_t)(b - 4097) * 256 + t;
        f32x4 z = (f32x4){0.f, 0.f, 0.f, 0.f};
        ((f32x4*)out)[2 * idx] = z;
        ((f32x4*)out)[2 * idx + 1] = z;
    }
}

// Grouped expert GEMM, 64x128 tile, BK=64, full K=2048 (32 steps).
// TRUE 2-phase pipeline (catalog T3+T4): per step
//   STAGE(next buf, 6 DMAs) -> s_waitcnt vmcnt(6) -> raw s_barrier
//   -> 16 MFMAs on current buf -> raw s_barrier
// Counted vmcnt keeps the 6 prefetch DMAs in flight ACROSS the barrier.
// vmcnt(0) only on the final step. 48 KB LDS -> 3 blocks/CU (12 waves).
// XOR-chunk swizzle (rule 21): linear LDS dest + inverse-swizzled global
// source chunk + same XOR on fragment-read address (proven 0 conflicts).
//
// EXPERT->XCD PINNING (this round): 1-D grid, flat = e + 8*(nt + 8*mz),
// so flat%8 = expert -> each XCD owns one expert; its working set
// (wT_e 4 MB + gathered xB_e ~2 MB) is L2-resident, turning A/B re-reads
// from contended L3/HBM traffic into local L2 hits. Real work is
// front-loaded (flat < ~600); tail blocks early-exit on cnt.
__global__ __launch_bounds__(256, 3) void gemm_kernel(
    const __bf16* __restrict__ xB, const __bf16* __restrict__ wT,
    const int* __restrict__ cnt, const int* __restrict__ rowlist,
    const float* __restrict__ topk_w, float* __restrict__ out) {
    const int flat = blockIdx.x;
    const int e  = flat & 7;          // flat%8 -> XCD id (expert-pinned)
    const int nt = (flat >> 3) & 7;
    const int mz = flat >> 6;
    const int cnt_e = cnt[e];
    const int m0 = mz * M_TILE;
    if (m0 >= cnt_e) return;
    const int n0 = nt * N_TILE;
    const int tid = threadIdx.x;
    const int lane = tid & 63;
    const int wave = tid >> 6;
    const int wm = wave & 1, wn = wave >> 1;

    __shared__ __bf16 As[2][M_TILE * BK];   // 2 x 8 KB
    __shared__ __bf16 Bs[2][N_TILE * BK];   // 2 x 16 KB

    const int* rl = rowlist + e * ROWS;

    const int lc = lane & 7;    // 16B chunk within a 128B row
    const int lr = lane >> 3;   // row within an 8-row DMA group
    const int cg = lc ^ lr;     // inverse-swizzled global chunk (row&7 == lr)

    // A: 2 DMA/wave cover rows 16w..16w+15 (gathered via rowlist)
    int gm0 = m0 + 16 * wave + lr;
    int gm1 = gm0 + 8;
    if (gm0 >= cnt_e) gm0 = cnt_e - 1;   // dup row, dropped in epilogue
    if (gm1 >= cnt_e) gm1 = cnt_e - 1;
    const __bf16* asrc0 = xB + (size_t)rl[gm0] * I_DIM + cg * 8;
    const __bf16* asrc1 = xB + (size_t)rl[gm1] * I_DIM + cg * 8;
    // B: 4 DMA/wave cover n-rows 32w..32w+31
    const __bf16* wTe = wT + (size_t)e * (H_DIM * I_DIM);
    const __bf16* bsrc = wTe + (size_t)(n0 + 32 * wave + lr) * I_DIM + cg * 8;

    // fragment-read offsets (elements), swizzled with the same XOR:
    // row = wm*32|wn*64 + f*16 + lm  ->  (row&7) == (lm&7)
    const int lm = lane & 15, lg = lane >> 4, sw = lm & 7;
    int offA[2][2], offB[2][4];
#pragma unroll
    for (int s = 0; s < 2; ++s) {
        int cs = (((s * 4) + lg) ^ sw) * 8;
#pragma unroll
        for (int mt = 0; mt < 2; ++mt)
            offA[s][mt] = (wm * 32 + mt * 16 + lm) * BK + cs;
#pragma unroll
        for (int nt2 = 0; nt2 < 4; ++nt2)
            offB[s][nt2] = (wn * 64 + nt2 * 16 + lm) * BK + cs;
    }

    f32x4 acc[2][4];
#pragma unroll
    for (int mt = 0; mt < 2; ++mt)
#pragma unroll
        for (int nt2 = 0; nt2 < 4; ++nt2)
            acc[mt][nt2] = (f32x4){0.f, 0.f, 0.f, 0.f};

#define STAGE(buf, koff)                                                  \
    do {                                                                  \
        load_lds16(asrc0 + (koff), &As[buf][wave * 1024]);                \
        load_lds16(asrc1 + (koff), &As[buf][wave * 1024 + 512]);          \
        load_lds16(bsrc + (koff),               &Bs[buf][wave * 2048]);   \
        load_lds16(bsrc +  8 * I_DIM + (koff),  &Bs[buf][wave * 2048 + 512]);  \
        load_lds16(bsrc + 16 * I_DIM + (koff),  &Bs[buf][wave * 2048 + 1024]); \
        load_lds16(bsrc + 24 * I_DIM + (koff),  &Bs[buf][wave * 2048 + 1536]); \
    } while (0)

    STAGE(0, 0);   // prologue: 6 DMAs in flight for step 0

    for (int t = 0; t < NSTEP; ++t) {
        const int cur = t & 1;
        if (t + 1 < NSTEP) {
            STAGE(cur ^ 1, (t + 1) * BK);                       // 12 in flight
            asm volatile("s_waitcnt vmcnt(6)" ::: "memory");    // step-t's 6 done
        } else {
            asm volatile("s_waitcnt vmcnt(0)" ::: "memory");    // drain last tile
        }
        __builtin_amdgcn_s_barrier();       // all waves: buf[cur] fully written
        asm volatile("" ::: "memory");      // keep ds_reads below the barrier

        const __bf16* Ab = As[cur];
        const __bf16* Bb = Bs[cur];
#pragma unroll
        for (int s = 0; s < 2; ++s) {
            bf16x8 af[2], bfr[4];
#pragma unroll
            for (int f = 0; f < 2; ++f) af[f] = *(const bf16x8*)&Ab[offA[s][f]];
#pragma unroll
            for (int f = 0; f < 4; ++f) bfr[f] = *(const bf16x8*)&Bb[offB[s][f]];
#pragma unroll
            for (int mt = 0; mt < 2; ++mt)
#pragma unroll
                for (int nt2 = 0; nt2 < 4; ++nt2)
                    acc[mt][nt2] = __builtin_amdgcn_mfma_f32_16x16x32_bf16(
                        af[mt], bfr[nt2], acc[mt][nt2], 0, 0, 0);
        }
        asm volatile("" ::: "memory");      // keep ds_reads above the barrier
        __builtin_amdgcn_s_barrier();       // all waves done reading buf[cur]
    }
#undef STAGE

    // epilogue: C/D col=lane&15, row=(lane>>4)*4+reg; scale by topk weight,
    // atomicAdd into out[token] (covers the topk-sum across experts)
    const int lq = lane >> 4, ln = lane & 15;
#pragma unroll
    for (int mt = 0; mt < 2; ++mt) {
#pragma unroll
        for (int j = 0; j < 4; ++j) {
            int gm = m0 + wm * 32 + mt * 16 + lq * 4 + j;
            if (gm < cnt_e) {
                int row = rl[gm];
                float tw = topk_w[row];
                float* orow = out + (size_t)(row >> 1) * H_DIM + n0 + wn * 64 + ln;
#pragma unroll
                for (int nt2 = 0; nt2 < 4; ++nt2)
                    atomicAdd(&orow[nt2 * 16], acc[mt][nt2][j] * tw);
            }
        }
    }
}

extern "C" void kernel_launch(void* const* d_in, const int* in_sizes, int n_in,
                              void* d_out, int out_size, void* d_ws, size_t ws_size,
                              hipStream_t stream) {
    const float* x      = (const float*)d_in[0];  // [ROWS, I_DIM] fp32
    const float* w      = (const float*)d_in[1];  // [E, I_DIM, H_DIM] fp32
    const float* logits = (const float*)d_in[2];  // [T, E] fp32
    float* out = (float*)d_out;                   // [T, H_DIM] fp32

    char* ws = (char*)d_ws;
    float*  topk_w  = (float*)ws;                                      // 16 KB
    int*    cnt     = (int*)(ws + 16384);                              // 128 B
    int*    rowlist = (int*)(ws + 16384 + 128);                        // 128 KB
    __bf16* wT      = (__bf16*)(ws + 16384 + 128 + 131072);            // 32 MB [E][H][I]
    __bf16* xB      = (__bf16*)(ws + 16384 + 128 + 131072 + 33554432); // 16 MB [ROWS][I]

    // prep: routing (1) + w transpose+convert (2048) + x convert (2048)
    //       + out zero (1024)
    prep_kernel<<<5121, 256, 0, stream>>>(w, x, logits, wT, xB, out, topk_w, cnt, rowlist);
    // 1-D grid, flat = e + 8*(nt + 8*mz): expert pinned to XCD, work
    // front-loaded, tail early-exits on cnt_e
    gemm_kernel<<<N_EXPERTS * (H_DIM / N_TILE) * (ROWS / M_TILE), 256, 0, stream>>>(
        xB, wT, cnt, rowlist, topk_w, out);
}